// Round 1
// baseline (779.238 us; speedup 1.0000x reference)
//
#include <hip/hip_runtime.h>
#include <math.h>

// Problem dims
#define B_ 8
#define N_ 512
#define T_ 64
#define D_ 128
#define E_ 32
#define M_ 3
#define BN_ 4096

// ws layout (float offsets)
#define OFF_U      0          // 384
#define OFF_C      384        // 384
#define OFF_QN     768        // 3*32*128 = 12288
#define OFF_H      13056      // 4096*128 = 524288
#define OFF_PROBS  537344     // 24
#define OFF_HV     537376     // 4096
#define OFF_SCORES 541472     // 768*512 = 393216
#define OFF_HMIX   934688     // 8*32*512 = 131072
#define OFF_EV     1065760    // 256

// ---------------------------------------------------------------------------
// prep: u = W_ih @ proj_W, c = W_ih @ proj_b + b_ih; qn = normalized queries
// ---------------------------------------------------------------------------
__global__ void prep_kernel(const float* __restrict__ Wih,
                            const float* __restrict__ projW,
                            const float* __restrict__ projb,
                            const float* __restrict__ bih,
                            const float* __restrict__ queries,
                            float* __restrict__ ws) {
  int tid = threadIdx.x;
  if (blockIdx.x == 0) {
    if (tid < 384) {
      float u = 0.f, c = 0.f;
      for (int d = 0; d < 128; ++d) {
        float w = Wih[tid * 128 + d];
        u += w * projW[d];
        c += w * projb[d];
      }
      ws[OFF_U + tid] = u;
      ws[OFF_C + tid] = c + bih[tid];
    }
  } else {
    if (tid < 96) {
      float ss = 0.f;
      for (int d = 0; d < 128; ++d) { float q = queries[tid * 128 + d]; ss += q * q; }
      float inv = 1.f / fmaxf(sqrtf(ss), 1e-12f);
      for (int d = 0; d < 128; ++d)
        ws[OFF_QN + tid * 128 + d] = queries[tid * 128 + d] * inv;
    }
  }
}

// ---------------------------------------------------------------------------
// GRU: 256 blocks x 512 threads; 16 sequences per block; W_hh in registers.
// Lane layout: jslot = lane>>2 (16 slots), kg = lane&3 (K split 4x32).
// Wave w owns j in [w*48, w*48+48): jb = w*48 + jslot*3, 3 rows per lane.
// Quad read order rotated by 2*kg so the 4 kg addresses hit disjoint banks.
// ---------------------------------------------------------------------------
__global__ __launch_bounds__(512) void gru_kernel(const float* __restrict__ x,
                                                  const float* __restrict__ Whh,
                                                  const float* __restrict__ bhh,
                                                  const float* __restrict__ outW,
                                                  float* __restrict__ ws) {
  __shared__ float hL[16 * 128];
  __shared__ float ghL[16 * 384];
  __shared__ float uL[384], cL[384];
  __shared__ float xsL[16];

  const int tid = threadIdx.x;
  const int wave = tid >> 6, lane = tid & 63;
  const int jslot = lane >> 2, kg = lane & 3;
  const int jb = wave * 48 + jslot * 3;

  // Load W_hh fragment into registers (rotated quad order)
  float4 Wr[3][8];
#pragma unroll
  for (int jj = 0; jj < 3; ++jj)
#pragma unroll
    for (int q = 0; q < 8; ++q) {
      int col = kg * 32 + ((q + 2 * kg) & 7) * 4;
      Wr[jj][q] = *(const float4*)&Whh[(jb + jj) * 128 + col];
    }
  float bh0 = bhh[jb], bh1 = bhh[jb + 1], bh2 = bhh[jb + 2];

  for (int i = tid; i < 384; i += 512) { uL[i] = ws[OFF_U + i]; cL[i] = ws[OFF_C + i]; }
  for (int i = tid; i < 2048; i += 512) hL[i] = 0.f;
  __syncthreads();

  const int seq0 = blockIdx.x * 16;

  for (int t = 0; t < 64; ++t) {
    if (tid < 16) {
      int r = (seq0 + tid) * 64 + t;
      int bb = r >> 15;
      int rem = r & 32767;
      int tt = rem >> 9;
      int nn = rem & 511;
      xsL[tid] = x[(bb * 512 + nn) * 64 + tt];
    }
    // phase 1: gh = W_hh @ h (per-sequence)
    for (int s = 0; s < 16; ++s) {
      float a0 = 0.f, a1 = 0.f, a2 = 0.f;
#pragma unroll
      for (int q = 0; q < 8; ++q) {
        int col = kg * 32 + ((q + 2 * kg) & 7) * 4;
        float4 hq = *(const float4*)&hL[s * 128 + col];
        a0 += Wr[0][q].x * hq.x + Wr[0][q].y * hq.y + Wr[0][q].z * hq.z + Wr[0][q].w * hq.w;
        a1 += Wr[1][q].x * hq.x + Wr[1][q].y * hq.y + Wr[1][q].z * hq.z + Wr[1][q].w * hq.w;
        a2 += Wr[2][q].x * hq.x + Wr[2][q].y * hq.y + Wr[2][q].z * hq.z + Wr[2][q].w * hq.w;
      }
      a0 += __shfl_xor(a0, 1); a0 += __shfl_xor(a0, 2);
      a1 += __shfl_xor(a1, 1); a1 += __shfl_xor(a1, 2);
      a2 += __shfl_xor(a2, 1); a2 += __shfl_xor(a2, 2);
      if (kg == 0) {
        ghL[s * 384 + jb + 0] = a0 + bh0;
        ghL[s * 384 + jb + 1] = a1 + bh1;
        ghL[s * 384 + jb + 2] = a2 + bh2;
      }
    }
    __syncthreads();
    // phase 2: gates + h update
#pragma unroll
    for (int p = 0; p < 4; ++p) {
      int item = tid + p * 512;
      int s = item >> 7, d = item & 127;
      float xs = xsL[s];
      float gr = xs * uL[d] + cL[d] + ghL[s * 384 + d];
      float gz = xs * uL[128 + d] + cL[128 + d] + ghL[s * 384 + 128 + d];
      float hn = ghL[s * 384 + 256 + d];
      float gn = xs * uL[256 + d] + cL[256 + d];
      float rr = 1.f / (1.f + expf(-gr));
      float zz = 1.f / (1.f + expf(-gz));
      float ng = tanhf(gn + rr * hn);
      float hold = hL[s * 128 + d];
      hL[s * 128 + d] = (1.f - zz) * ng + zz * hold;
    }
    __syncthreads();
  }

  // write final h and hv = h . out_W
  float* h_out = ws + OFF_H;
#pragma unroll
  for (int p = 0; p < 4; ++p) {
    int item = tid + p * 512;
    int s = item >> 7, d = item & 127;
    h_out[(seq0 + s) * 128 + d] = hL[s * 128 + d];
  }
  for (int s = wave; s < 16; s += 8) {
    float a = hL[s * 128 + lane] * outW[lane] + hL[s * 128 + 64 + lane] * outW[64 + lane];
    for (int off = 32; off; off >>= 1) a += __shfl_xor(a, off);
    if (lane == 0) ws[OFF_HV + seq0 + s] = a;
  }
}

// ---------------------------------------------------------------------------
// stats + router softmax: one block per b (128 threads, thread = d)
// ---------------------------------------------------------------------------
__global__ void stats_kernel(const float* __restrict__ routerW,
                             const float* __restrict__ routerb,
                             float* __restrict__ ws,
                             float* __restrict__ d_out) {
  int b = blockIdx.x, tid = threadIdx.x;
  const float* h = ws + OFF_H;
  __shared__ float st[256];
  __shared__ float lg[3];
  float sum = 0.f, sumsq = 0.f;
  for (int n = 0; n < 512; ++n) {
    float v = h[(b * 512 + n) * 128 + tid];
    sum += v; sumsq += v * v;
  }
  float mean = sum * (1.f / 512.f);
  float var = (sumsq - 512.f * mean * mean) * (1.f / 511.f);  // ddof=1
  st[tid] = mean;
  st[128 + tid] = sqrtf(fmaxf(var, 0.f));
  __syncthreads();
  if (tid < 3) {
    float acc = routerb[tid];
    for (int q = 0; q < 256; ++q) acc += st[q] * routerW[tid * 256 + q];
    lg[tid] = acc;
  }
  __syncthreads();
  if (tid == 0) {
    float mx = fmaxf(lg[0], fmaxf(lg[1], lg[2]));
    float e0 = expf(lg[0] - mx), e1 = expf(lg[1] - mx), e2 = expf(lg[2] - mx);
    float inv = 1.f / (e0 + e1 + e2);
    ws[OFF_PROBS + b * 3 + 0] = e0 * inv;
    ws[OFF_PROBS + b * 3 + 1] = e1 * inv;
    ws[OFF_PROBS + b * 3 + 2] = e2 * inv;
    d_out[4096 + b * 3 + 0] = e0 * inv;
    d_out[4096 + b * 3 + 1] = e1 * inv;
    d_out[4096 + b * 3 + 2] = e2 * inv;
  }
}

// ---------------------------------------------------------------------------
// scores[b,m,e,n] = qn[m,e,:] . (space_W[m]@h[b,n] + space_b[m]) / ||hs||
// grid (b,m,nchunk) = 8*3*16; block 256 handles 2 n's at a time.
// ---------------------------------------------------------------------------
#define WP 132
__global__ __launch_bounds__(256) void scores_kernel(const float* __restrict__ spaceW,
                                                     const float* __restrict__ spaceb,
                                                     float* __restrict__ ws) {
  int bz = blockIdx.x;
  int b = bz / 48, rem = bz % 48, m = rem / 16, chunk = rem % 16;
  int n0 = chunk * 32;
  int tid = threadIdx.x;
  const float* h = ws + OFF_H;
  const float* qn = ws + OFF_QN;
  float* scores = ws + OFF_SCORES;

  __shared__ float WmL[128 * WP];
  __shared__ float hL2[2 * 128];
  __shared__ float hsL[2 * 128];
  __shared__ float spart[2 * 4 * 32];
  __shared__ float normL[2];

  for (int i = tid; i < 16384; i += 256)
    WmL[(i >> 7) * WP + (i & 127)] = spaceW[m * 16384 + i];
  __syncthreads();

  int nn = tid >> 7, k = tid & 127;
  for (int pair = 0; pair < 16; ++pair) {
    int n = n0 + pair * 2;
    hL2[tid] = h[(b * 512 + n + nn) * 128 + k];
    __syncthreads();
    float acc = spaceb[m * 128 + k];
#pragma unroll
    for (int d4 = 0; d4 < 32; ++d4) {
      float4 w4 = *(const float4*)&WmL[k * WP + d4 * 4];
      float4 h4 = *(const float4*)&hL2[nn * 128 + d4 * 4];
      acc += w4.x * h4.x + w4.y * h4.y + w4.z * h4.z + w4.w * h4.w;
    }
    hsL[nn * 128 + k] = acc;
    __syncthreads();
    if ((tid & 127) < 64) {  // waves 0 (nn=0) and 2 (nn=1)
      int lane = tid & 63;
      float v0 = hsL[nn * 128 + lane], v1 = hsL[nn * 128 + 64 + lane];
      float ss = v0 * v0 + v1 * v1;
      for (int off = 32; off; off >>= 1) ss += __shfl_xor(ss, off);
      if (lane == 0) normL[nn] = fmaxf(sqrtf(ss), 1e-12f);
    }
    __syncthreads();
    int e = tid & 31, dq = (tid >> 5) & 3;
    float p = 0.f;
#pragma unroll 8
    for (int dd = 0; dd < 32; ++dd)
      p += qn[(m * 32 + e) * 128 + dq * 32 + dd] * hsL[nn * 128 + dq * 32 + dd];
    spart[(nn * 4 + dq) * 32 + e] = p;
    __syncthreads();
    if (tid < 64) {
      int nn2 = tid >> 5, e2 = tid & 31;
      float s = spart[(nn2 * 4 + 0) * 32 + e2] + spart[(nn2 * 4 + 1) * 32 + e2] +
                spart[(nn2 * 4 + 2) * 32 + e2] + spart[(nn2 * 4 + 3) * 32 + e2];
      scores[((b * 3 + m) * 32 + e2) * 512 + n + nn2] = s / normL[nn2];
    }
    __syncthreads();
  }
}

// ---------------------------------------------------------------------------
// top-25 per (b,m,e) row + softmax(vals/0.7) + scatter into Hmix (weighted by probs)
// one wave per row; ties resolved to lower index (matches lax.top_k)
// ---------------------------------------------------------------------------
__global__ __launch_bounds__(256) void topk_kernel(float* __restrict__ ws) {
  int row = blockIdx.x * 4 + (threadIdx.x >> 6);  // [0,768)
  int lane = threadIdx.x & 63;
  int b = row / 96;
  int m = (row / 32) % 3;
  int e = row & 31;
  const float* sc = ws + OFF_SCORES + row * 512;
  float prob = ws[OFF_PROBS + b * 3 + m];

  float v[8];
#pragma unroll
  for (int j = 0; j < 8; ++j) v[j] = sc[j * 64 + lane];

  float selv = 0.f; int seli = 0; float maxv = 0.f;
  for (int it = 0; it < 25; ++it) {
    float bv = v[0]; int bj = 0;
#pragma unroll
    for (int j = 1; j < 8; ++j)
      if (v[j] > bv) { bv = v[j]; bj = j; }
    int bidx = bj * 64 + lane;
    for (int off = 32; off; off >>= 1) {
      float ov = __shfl_xor(bv, off);
      int oi = __shfl_xor(bidx, off);
      if (ov > bv || (ov == bv && oi < bidx)) { bv = ov; bidx = oi; }
    }
    if (lane == (bidx & 63)) v[bidx >> 6] = -INFINITY;
    if (it == 0) maxv = bv;
    if (lane == it) { selv = bv; seli = bidx; }
  }
  float ex = (lane < 25) ? expf((selv - maxv) * (1.f / 0.7f)) : 0.f;
  float den = ex;
  for (int off = 32; off; off >>= 1) den += __shfl_xor(den, off);
  if (lane < 25)
    atomicAdd(&ws[OFF_HMIX + (b * 32 + e) * 512 + seli], prob * ex / den);
}

// ---------------------------------------------------------------------------
// ev[b,e] = sum_n Hmix[b,e,n] * hv[b,n]   (one wave per row)
// ---------------------------------------------------------------------------
__global__ void ev_kernel(float* __restrict__ ws) {
  int row = blockIdx.x * 4 + (threadIdx.x >> 6);  // [0,256)
  int lane = threadIdx.x & 63;
  int b = row >> 5;
  const float* Hm = ws + OFF_HMIX + row * 512;
  const float* hv = ws + OFF_HV + b * 512;
  float a = 0.f;
#pragma unroll
  for (int j = 0; j < 8; ++j) a += Hm[j * 64 + lane] * hv[j * 64 + lane];
  for (int off = 32; off; off >>= 1) a += __shfl_xor(a, off);
  if (lane == 0) ws[OFF_EV + row] = a;
}

// ---------------------------------------------------------------------------
// out[b,n] = alpha * (prior @ hv)[b,n] + (1-alpha) * sum_e Hmix[b,e,n]*ev[b,e] + out_b
// one wave per (b,n)
// ---------------------------------------------------------------------------
__global__ void final_kernel(const float* __restrict__ prior,
                             const float* __restrict__ outb,
                             const float* __restrict__ plog,
                             float* __restrict__ ws,
                             float* __restrict__ d_out) {
  int row = blockIdx.x * 4 + (threadIdx.x >> 6);  // [0,4096)
  int lane = threadIdx.x & 63;
  int b = row >> 9, n = row & 511;
  float alpha = 1.f / (1.f + expf(-plog[0]));
  const float* hv = ws + OFF_HV + b * 512;
  const float* pr = prior + n * 512;
  float s1 = 0.f;
#pragma unroll
  for (int j = 0; j < 8; ++j) s1 += pr[j * 64 + lane] * hv[j * 64 + lane];
  float s2 = 0.f;
  if (lane < 32) s2 = ws[OFF_HMIX + (b * 32 + lane) * 512 + n] * ws[OFF_EV + b * 32 + lane];
  float a = alpha * s1 + (1.f - alpha) * s2;
  for (int off = 32; off; off >>= 1) a += __shfl_xor(a, off);
  if (lane == 0) d_out[row] = a + outb[0];
}

// ---------------------------------------------------------------------------
extern "C" void kernel_launch(void* const* d_in, const int* in_sizes, int n_in,
                              void* d_out, int out_size, void* d_ws, size_t ws_size,
                              hipStream_t stream) {
  const float* x       = (const float*)d_in[0];
  const float* prior   = (const float*)d_in[1];
  const float* projW   = (const float*)d_in[2];
  const float* projb   = (const float*)d_in[3];
  const float* Wih     = (const float*)d_in[4];
  const float* Whh     = (const float*)d_in[5];
  const float* bih     = (const float*)d_in[6];
  const float* bhh     = (const float*)d_in[7];
  const float* spaceW  = (const float*)d_in[8];
  const float* spaceb  = (const float*)d_in[9];
  const float* routerW = (const float*)d_in[10];
  const float* routerb = (const float*)d_in[11];
  const float* outW    = (const float*)d_in[12];
  const float* outb    = (const float*)d_in[13];
  const float* plog    = (const float*)d_in[14];
  const float* queries = (const float*)d_in[15];
  float* ws  = (float*)d_ws;
  float* out = (float*)d_out;

  hipMemsetAsync(ws + OFF_HMIX, 0, 131072 * sizeof(float), stream);
  prep_kernel<<<2, 384, 0, stream>>>(Wih, projW, projb, bih, queries, ws);
  gru_kernel<<<256, 512, 0, stream>>>(x, Whh, bhh, outW, ws);
  stats_kernel<<<8, 128, 0, stream>>>(routerW, routerb, ws, out);
  scores_kernel<<<384, 256, 0, stream>>>(spaceW, spaceb, ws);
  topk_kernel<<<192, 256, 0, stream>>>(ws);
  ev_kernel<<<64, 256, 0, stream>>>(ws);
  final_kernel<<<1024, 256, 0, stream>>>(prior, outb, plog, ws, out);
}

// Round 2
// 330.186 us; speedup vs baseline: 2.3600x; 2.3600x over previous
//
#include <hip/hip_runtime.h>
#include <math.h>

// Problem dims
#define B_ 8
#define N_ 512
#define T_ 64
#define D_ 128
#define E_ 32
#define M_ 3
#define BN_ 4096

// ws layout (float offsets)
#define OFF_U      0          // 384
#define OFF_C      384        // 384
#define OFF_QN     768        // 3*32*128 = 12288
#define OFF_H      13056      // 4096*128 = 524288
#define OFF_PROBS  537344     // 24
#define OFF_HV     537376     // 4096
#define OFF_SCORES 541472     // 768*512 = 393216
#define OFF_HMIX   934688     // 8*32*512 = 131072
#define OFF_EV     1065760    // 256
#define OFF_WHI    1066016    // 384*128 bf16 = 24576 floats
#define OFF_WLO    1090592    // 24576 floats

typedef short bf16x8 __attribute__((ext_vector_type(8)));
typedef float f32x4 __attribute__((ext_vector_type(4)));

__device__ __forceinline__ unsigned short bf16_rtn(float f) {
  unsigned int u = __float_as_uint(f);
  return (unsigned short)((u + 0x7FFFu + ((u >> 16) & 1u)) >> 16);
}
__device__ __forceinline__ float bf16_f(unsigned short h) {
  return __uint_as_float(((unsigned int)h) << 16);
}

// ---------------------------------------------------------------------------
// prep: u = W_ih @ proj_W, c = W_ih @ proj_b + b_ih; qn = normalized queries;
// W_hh split into bf16 hi/lo planes.
// ---------------------------------------------------------------------------
__global__ void prep_kernel(const float* __restrict__ Wih,
                            const float* __restrict__ projW,
                            const float* __restrict__ projb,
                            const float* __restrict__ bih,
                            const float* __restrict__ queries,
                            const float* __restrict__ Whh,
                            float* __restrict__ ws) {
  int tid = threadIdx.x;
  if (blockIdx.x == 0) {
    if (tid < 384) {
      float u = 0.f, c = 0.f;
      for (int d = 0; d < 128; ++d) {
        float w = Wih[tid * 128 + d];
        u += w * projW[d];
        c += w * projb[d];
      }
      ws[OFF_U + tid] = u;
      ws[OFF_C + tid] = c + bih[tid];
    }
  } else if (blockIdx.x == 1) {
    if (tid < 96) {
      float ss = 0.f;
      for (int d = 0; d < 128; ++d) { float q = queries[tid * 128 + d]; ss += q * q; }
      float inv = 1.f / fmaxf(sqrtf(ss), 1e-12f);
      for (int d = 0; d < 128; ++d)
        ws[OFF_QN + tid * 128 + d] = queries[tid * 128 + d] * inv;
    }
  } else {
    unsigned short* WHI = (unsigned short*)(ws + OFF_WHI);
    unsigned short* WLO = (unsigned short*)(ws + OFF_WLO);
    for (int i = tid; i < 49152; i += 384) {
      float w = Whh[i];
      unsigned short hi = bf16_rtn(w);
      WHI[i] = hi;
      WLO[i] = bf16_rtn(w - bf16_f(hi));
    }
  }
}

// ---------------------------------------------------------------------------
// GRU via split-bf16 MFMA. 256 blocks x 512 threads, 16 seqs/block.
// Per step: gh[s][j] = sum_k h[s][k] W[j][k] via mfma_f32_16x16x32_bf16,
// 3 passes (Whi*hhi + Whi*hlo + Wlo*hhi). W frags persist in registers.
// h hi/lo planes kept in LDS in A-fragment order: cell(g=k>>3, s) at
// pitch-17 cells of 8 bf16 -> conflict-free ds_read_b128.
// ---------------------------------------------------------------------------
__global__ __launch_bounds__(512, 2) void gru_kernel(const float* __restrict__ x,
                                                     const float* __restrict__ bhh,
                                                     const float* __restrict__ outW,
                                                     float* __restrict__ ws) {
  __shared__ float ghL[16 * 388];                 // [s][j], pitch 388
  __shared__ float hL[16 * 128];                  // fp32 h
  __shared__ __align__(16) unsigned short hHi[16 * 17 * 8];
  __shared__ __align__(16) unsigned short hLo[16 * 17 * 8];
  __shared__ float uL[384], cL[384];
  __shared__ float xsL[16];

  const int tid = threadIdx.x, wave = tid >> 6, lane = tid & 63;
  const int q = lane >> 4, s15 = lane & 15;
  const unsigned short* WHI = (const unsigned short*)(ws + OFF_WHI);
  const unsigned short* WLO = (const unsigned short*)(ws + OFF_WLO);

  // persistent B fragments: wave handles j-tiles wave*3 .. wave*3+2
  bf16x8 Bhi[3][4], Blo[3][4];
  float bj[3];
#pragma unroll
  for (int tt = 0; tt < 3; ++tt) {
    int row = (wave * 3 + tt) * 16 + s15;
    bj[tt] = bhh[row];
#pragma unroll
    for (int c = 0; c < 4; ++c) {
      Bhi[tt][c] = *(const bf16x8*)&WHI[row * 128 + c * 32 + q * 8];
      Blo[tt][c] = *(const bf16x8*)&WLO[row * 128 + c * 32 + q * 8];
    }
  }

  for (int i = tid; i < 2048; i += 512) hL[i] = 0.f;
  for (int i = tid; i < 2176; i += 512) { hHi[i] = 0; hLo[i] = 0; }
  for (int i = tid; i < 384; i += 512) { uL[i] = ws[OFF_U + i]; cL[i] = ws[OFF_C + i]; }
  __syncthreads();

  const int seq0 = blockIdx.x * 16;
  const int ps = tid >> 5;        // phase-2 sequence 0..15
  const int pd = (tid & 31) * 4;  // phase-2 d (4 consecutive)

  for (int t = 0; t < 64; ++t) {
    if (tid < 16) {
      int r = (seq0 + tid) * 64 + t;
      xsL[tid] = x[((r >> 15) * 512 + (r & 511)) * 64 + ((r >> 9) & 63)];
    }
    // ---- phase 1: MFMA ----
    f32x4 acc0 = {0.f, 0.f, 0.f, 0.f};
    f32x4 acc1 = {0.f, 0.f, 0.f, 0.f};
    f32x4 acc2 = {0.f, 0.f, 0.f, 0.f};
#pragma unroll
    for (int c = 0; c < 4; ++c) {
      bf16x8 Ahi = *(const bf16x8*)&hHi[((c * 4 + q) * 17 + s15) * 8];
      bf16x8 Alo = *(const bf16x8*)&hLo[((c * 4 + q) * 17 + s15) * 8];
      acc0 = __builtin_amdgcn_mfma_f32_16x16x32_bf16(Ahi, Bhi[0][c], acc0, 0, 0, 0);
      acc1 = __builtin_amdgcn_mfma_f32_16x16x32_bf16(Ahi, Bhi[1][c], acc1, 0, 0, 0);
      acc2 = __builtin_amdgcn_mfma_f32_16x16x32_bf16(Ahi, Bhi[2][c], acc2, 0, 0, 0);
      acc0 = __builtin_amdgcn_mfma_f32_16x16x32_bf16(Alo, Bhi[0][c], acc0, 0, 0, 0);
      acc1 = __builtin_amdgcn_mfma_f32_16x16x32_bf16(Alo, Bhi[1][c], acc1, 0, 0, 0);
      acc2 = __builtin_amdgcn_mfma_f32_16x16x32_bf16(Alo, Bhi[2][c], acc2, 0, 0, 0);
      acc0 = __builtin_amdgcn_mfma_f32_16x16x32_bf16(Ahi, Blo[0][c], acc0, 0, 0, 0);
      acc1 = __builtin_amdgcn_mfma_f32_16x16x32_bf16(Ahi, Blo[1][c], acc1, 0, 0, 0);
      acc2 = __builtin_amdgcn_mfma_f32_16x16x32_bf16(Ahi, Blo[2][c], acc2, 0, 0, 0);
    }
    // D-layout: lane holds gh[s = q*4+r][j = jt*16 + s15]
#pragma unroll
    for (int r = 0; r < 4; ++r) {
      int srow = q * 4 + r;
      ghL[srow * 388 + (wave * 3 + 0) * 16 + s15] = acc0[r] + bj[0];
      ghL[srow * 388 + (wave * 3 + 1) * 16 + s15] = acc1[r] + bj[1];
      ghL[srow * 388 + (wave * 3 + 2) * 16 + s15] = acc2[r] + bj[2];
    }
    __syncthreads();
    // ---- phase 2: gates, float4 per thread ----
    {
      float xs = xsL[ps];
      float4 ghr = *(const float4*)&ghL[ps * 388 + pd];
      float4 ghz = *(const float4*)&ghL[ps * 388 + 128 + pd];
      float4 ghn = *(const float4*)&ghL[ps * 388 + 256 + pd];
      float4 ur = *(const float4*)&uL[pd];
      float4 uz = *(const float4*)&uL[128 + pd];
      float4 un = *(const float4*)&uL[256 + pd];
      float4 cr = *(const float4*)&cL[pd];
      float4 cz = *(const float4*)&cL[128 + pd];
      float4 cn = *(const float4*)&cL[256 + pd];
      float4 hold = *(const float4*)&hL[ps * 128 + pd];
      float hn[4];
      unsigned short hib[4], lob[4];
      const float* pghr = (const float*)&ghr;
      const float* pghz = (const float*)&ghz;
      const float* pghn = (const float*)&ghn;
      const float* pur = (const float*)&ur;
      const float* puz = (const float*)&uz;
      const float* pun = (const float*)&un;
      const float* pcr = (const float*)&cr;
      const float* pcz = (const float*)&cz;
      const float* pcn = (const float*)&cn;
      const float* phold = (const float*)&hold;
#pragma unroll
      for (int i = 0; i < 4; ++i) {
        float gr = xs * pur[i] + pcr[i] + pghr[i];
        float gz = xs * puz[i] + pcz[i] + pghz[i];
        float gn = xs * pun[i] + pcn[i];
        float rr = 1.f / (1.f + __expf(-gr));
        float zz = 1.f / (1.f + __expf(-gz));
        float a = gn + rr * pghn[i];
        float ng = 1.f - 2.f / (__expf(2.f * a) + 1.f);  // tanh(a)
        float hv = (1.f - zz) * ng + zz * phold[i];
        hn[i] = hv;
        unsigned short hi = bf16_rtn(hv);
        hib[i] = hi;
        lob[i] = bf16_rtn(hv - bf16_f(hi));
      }
      float4 hnew = make_float4(hn[0], hn[1], hn[2], hn[3]);
      *(float4*)&hL[ps * 128 + pd] = hnew;
      uint2 hp, lp;
      hp.x = (unsigned int)hib[0] | ((unsigned int)hib[1] << 16);
      hp.y = (unsigned int)hib[2] | ((unsigned int)hib[3] << 16);
      lp.x = (unsigned int)lob[0] | ((unsigned int)lob[1] << 16);
      lp.y = (unsigned int)lob[2] | ((unsigned int)lob[3] << 16);
      int g = pd >> 3, e = pd & 7;
      *(uint2*)&hHi[(g * 17 + ps) * 8 + e] = hp;
      *(uint2*)&hLo[(g * 17 + ps) * 8 + e] = lp;
    }
    __syncthreads();
  }

  // write final h and hv = h . out_W
  float* h_out = ws + OFF_H;
#pragma unroll
  for (int p = 0; p < 4; ++p) {
    int item = tid + p * 512;
    int s = item >> 7, d = item & 127;
    h_out[(seq0 + s) * 128 + d] = hL[s * 128 + d];
  }
  for (int s = wave; s < 16; s += 8) {
    float a = hL[s * 128 + lane] * outW[lane] + hL[s * 128 + 64 + lane] * outW[64 + lane];
    for (int off = 32; off; off >>= 1) a += __shfl_xor(a, off);
    if (lane == 0) ws[OFF_HV + seq0 + s] = a;
  }
}

// ---------------------------------------------------------------------------
// stats + router softmax: one block per b (128 threads, thread = d)
// ---------------------------------------------------------------------------
__global__ void stats_kernel(const float* __restrict__ routerW,
                             const float* __restrict__ routerb,
                             float* __restrict__ ws,
                             float* __restrict__ d_out) {
  int b = blockIdx.x, tid = threadIdx.x;
  const float* h = ws + OFF_H;
  __shared__ float st[256];
  __shared__ float lg[3];
  float sum = 0.f, sumsq = 0.f;
  for (int n = 0; n < 512; ++n) {
    float v = h[(b * 512 + n) * 128 + tid];
    sum += v; sumsq += v * v;
  }
  float mean = sum * (1.f / 512.f);
  float var = (sumsq - 512.f * mean * mean) * (1.f / 511.f);  // ddof=1
  st[tid] = mean;
  st[128 + tid] = sqrtf(fmaxf(var, 0.f));
  __syncthreads();
  if (tid < 3) {
    float acc = routerb[tid];
    for (int q = 0; q < 256; ++q) acc += st[q] * routerW[tid * 256 + q];
    lg[tid] = acc;
  }
  __syncthreads();
  if (tid == 0) {
    float mx = fmaxf(lg[0], fmaxf(lg[1], lg[2]));
    float e0 = expf(lg[0] - mx), e1 = expf(lg[1] - mx), e2 = expf(lg[2] - mx);
    float inv = 1.f / (e0 + e1 + e2);
    ws[OFF_PROBS + b * 3 + 0] = e0 * inv;
    ws[OFF_PROBS + b * 3 + 1] = e1 * inv;
    ws[OFF_PROBS + b * 3 + 2] = e2 * inv;
    d_out[4096 + b * 3 + 0] = e0 * inv;
    d_out[4096 + b * 3 + 1] = e1 * inv;
    d_out[4096 + b * 3 + 2] = e2 * inv;
  }
}

// ---------------------------------------------------------------------------
// scores[b,m,e,n] = qn[m,e,:] . (space_W[m]@h[b,n] + space_b[m]) / ||hs||
// grid (b,m,nchunk) = 8*3*16; block 256 handles 2 n's at a time.
// ---------------------------------------------------------------------------
#define WP 132
__global__ __launch_bounds__(256) void scores_kernel(const float* __restrict__ spaceW,
                                                     const float* __restrict__ spaceb,
                                                     float* __restrict__ ws) {
  int bz = blockIdx.x;
  int b = bz / 48, rem = bz % 48, m = rem / 16, chunk = rem % 16;
  int n0 = chunk * 32;
  int tid = threadIdx.x;
  const float* h = ws + OFF_H;
  const float* qn = ws + OFF_QN;
  float* scores = ws + OFF_SCORES;

  __shared__ float WmL[128 * WP];
  __shared__ float hL2[2 * 128];
  __shared__ float hsL[2 * 128];
  __shared__ float spart[2 * 4 * 32];
  __shared__ float normL[2];

  for (int i = tid; i < 16384; i += 256)
    WmL[(i >> 7) * WP + (i & 127)] = spaceW[m * 16384 + i];
  __syncthreads();

  int nn = tid >> 7, k = tid & 127;
  for (int pair = 0; pair < 16; ++pair) {
    int n = n0 + pair * 2;
    hL2[tid] = h[(b * 512 + n + nn) * 128 + k];
    __syncthreads();
    float acc = spaceb[m * 128 + k];
#pragma unroll
    for (int d4 = 0; d4 < 32; ++d4) {
      float4 w4 = *(const float4*)&WmL[k * WP + d4 * 4];
      float4 h4 = *(const float4*)&hL2[nn * 128 + d4 * 4];
      acc += w4.x * h4.x + w4.y * h4.y + w4.z * h4.z + w4.w * h4.w;
    }
    hsL[nn * 128 + k] = acc;
    __syncthreads();
    if ((tid & 127) < 64) {
      int lane = tid & 63;
      float v0 = hsL[nn * 128 + lane], v1 = hsL[nn * 128 + 64 + lane];
      float ss = v0 * v0 + v1 * v1;
      for (int off = 32; off; off >>= 1) ss += __shfl_xor(ss, off);
      if (lane == 0) normL[nn] = fmaxf(sqrtf(ss), 1e-12f);
    }
    __syncthreads();
    int e = tid & 31, dq = (tid >> 5) & 3;
    float p = 0.f;
#pragma unroll 8
    for (int dd = 0; dd < 32; ++dd)
      p += qn[(m * 32 + e) * 128 + dq * 32 + dd] * hsL[nn * 128 + dq * 32 + dd];
    spart[(nn * 4 + dq) * 32 + e] = p;
    __syncthreads();
    if (tid < 64) {
      int nn2 = tid >> 5, e2 = tid & 31;
      float s = spart[(nn2 * 4 + 0) * 32 + e2] + spart[(nn2 * 4 + 1) * 32 + e2] +
                spart[(nn2 * 4 + 2) * 32 + e2] + spart[(nn2 * 4 + 3) * 32 + e2];
      scores[((b * 3 + m) * 32 + e2) * 512 + n + nn2] = s / normL[nn2];
    }
    __syncthreads();
  }
}

// ---------------------------------------------------------------------------
// top-25 per (b,m,e) row + softmax(vals/0.7) + scatter into Hmix (weighted by probs)
// ---------------------------------------------------------------------------
__global__ __launch_bounds__(256) void topk_kernel(float* __restrict__ ws) {
  int row = blockIdx.x * 4 + (threadIdx.x >> 6);  // [0,768)
  int lane = threadIdx.x & 63;
  int b = row / 96;
  int m = (row / 32) % 3;
  int e = row & 31;
  const float* sc = ws + OFF_SCORES + row * 512;
  float prob = ws[OFF_PROBS + b * 3 + m];

  float v[8];
#pragma unroll
  for (int j = 0; j < 8; ++j) v[j] = sc[j * 64 + lane];

  float selv = 0.f; int seli = 0; float maxv = 0.f;
  for (int it = 0; it < 25; ++it) {
    float bv = v[0]; int bj = 0;
#pragma unroll
    for (int j = 1; j < 8; ++j)
      if (v[j] > bv) { bv = v[j]; bj = j; }
    int bidx = bj * 64 + lane;
    for (int off = 32; off; off >>= 1) {
      float ov = __shfl_xor(bv, off);
      int oi = __shfl_xor(bidx, off);
      if (ov > bv || (ov == bv && oi < bidx)) { bv = ov; bidx = oi; }
    }
    if (lane == (bidx & 63)) v[bidx >> 6] = -INFINITY;
    if (it == 0) maxv = bv;
    if (lane == it) { selv = bv; seli = bidx; }
  }
  float ex = (lane < 25) ? __expf((selv - maxv) * (1.f / 0.7f)) : 0.f;
  float den = ex;
  for (int off = 32; off; off >>= 1) den += __shfl_xor(den, off);
  if (lane < 25)
    atomicAdd(&ws[OFF_HMIX + (b * 32 + e) * 512 + seli], prob * ex / den);
}

// ---------------------------------------------------------------------------
// ev[b,e] = sum_n Hmix[b,e,n] * hv[b,n]
// ---------------------------------------------------------------------------
__global__ void ev_kernel(float* __restrict__ ws) {
  int row = blockIdx.x * 4 + (threadIdx.x >> 6);  // [0,256)
  int lane = threadIdx.x & 63;
  int b = row >> 5;
  const float* Hm = ws + OFF_HMIX + row * 512;
  const float* hv = ws + OFF_HV + b * 512;
  float a = 0.f;
#pragma unroll
  for (int j = 0; j < 8; ++j) a += Hm[j * 64 + lane] * hv[j * 64 + lane];
  for (int off = 32; off; off >>= 1) a += __shfl_xor(a, off);
  if (lane == 0) ws[OFF_EV + row] = a;
}

// ---------------------------------------------------------------------------
// out[b,n] = alpha*(prior@hv)[b,n] + (1-alpha)*sum_e Hmix[b,e,n]*ev[b,e] + out_b
// ---------------------------------------------------------------------------
__global__ void final_kernel(const float* __restrict__ prior,
                             const float* __restrict__ outb,
                             const float* __restrict__ plog,
                             float* __restrict__ ws,
                             float* __restrict__ d_out) {
  int row = blockIdx.x * 4 + (threadIdx.x >> 6);  // [0,4096)
  int lane = threadIdx.x & 63;
  int b = row >> 9, n = row & 511;
  float alpha = 1.f / (1.f + expf(-plog[0]));
  const float* hv = ws + OFF_HV + b * 512;
  const float* pr = prior + n * 512;
  float s1 = 0.f;
#pragma unroll
  for (int j = 0; j < 8; ++j) s1 += pr[j * 64 + lane] * hv[j * 64 + lane];
  float s2 = 0.f;
  if (lane < 32) s2 = ws[OFF_HMIX + (b * 32 + lane) * 512 + n] * ws[OFF_EV + b * 32 + lane];
  float a = alpha * s1 + (1.f - alpha) * s2;
  for (int off = 32; off; off >>= 1) a += __shfl_xor(a, off);
  if (lane == 0) d_out[row] = a + outb[0];
}

// ---------------------------------------------------------------------------
extern "C" void kernel_launch(void* const* d_in, const int* in_sizes, int n_in,
                              void* d_out, int out_size, void* d_ws, size_t ws_size,
                              hipStream_t stream) {
  const float* x       = (const float*)d_in[0];
  const float* prior   = (const float*)d_in[1];
  const float* projW   = (const float*)d_in[2];
  const float* projb   = (const float*)d_in[3];
  const float* Wih     = (const float*)d_in[4];
  const float* Whh     = (const float*)d_in[5];
  const float* bih     = (const float*)d_in[6];
  const float* bhh     = (const float*)d_in[7];
  const float* spaceW  = (const float*)d_in[8];
  const float* spaceb  = (const float*)d_in[9];
  const float* routerW = (const float*)d_in[10];
  const float* routerb = (const float*)d_in[11];
  const float* outW    = (const float*)d_in[12];
  const float* outb    = (const float*)d_in[13];
  const float* plog    = (const float*)d_in[14];
  const float* queries = (const float*)d_in[15];
  float* ws  = (float*)d_ws;
  float* out = (float*)d_out;

  hipMemsetAsync(ws + OFF_HMIX, 0, 131072 * sizeof(float), stream);
  prep_kernel<<<3, 384, 0, stream>>>(Wih, projW, projb, bih, queries, Whh, ws);
  gru_kernel<<<256, 512, 0, stream>>>(x, bhh, outW, ws);
  stats_kernel<<<8, 128, 0, stream>>>(routerW, routerb, ws, out);
  scores_kernel<<<384, 256, 0, stream>>>(spaceW, spaceb, ws);
  topk_kernel<<<192, 256, 0, stream>>>(ws);
  ev_kernel<<<64, 256, 0, stream>>>(ws);
  final_kernel<<<1024, 256, 0, stream>>>(prior, outb, plog, ws, out);
}

// Round 3
// 261.028 us; speedup vs baseline: 2.9853x; 1.2649x over previous
//
#include <hip/hip_runtime.h>
#include <math.h>

// Problem dims
#define B_ 8
#define N_ 512
#define T_ 64
#define D_ 128
#define E_ 32
#define M_ 3
#define BN_ 4096

// ws layout (float offsets)
#define OFF_U      0          // 384
#define OFF_C      384        // 384
#define OFF_QN     768        // 3*32*128 = 12288
#define OFF_H      13056      // 4096*128 = 524288
#define OFF_PROBS  537344     // 24
#define OFF_HV     537376     // 4096
#define OFF_SCORES 541472     // 768*512 = 393216
#define OFF_HMIX   934688     // 8*32*512 = 131072
#define OFF_EV     1065760    // 256
#define OFF_WHI    1066016    // 384*128 bf16 = 24576 floats
#define OFF_WLO    1090592    // 24576 floats

typedef short bf16x8 __attribute__((ext_vector_type(8)));
typedef float f32x4 __attribute__((ext_vector_type(4)));

__device__ __forceinline__ unsigned short bf16_rtn(float f) {
  unsigned int u = __float_as_uint(f);
  return (unsigned short)((u + 0x7FFFu + ((u >> 16) & 1u)) >> 16);
}
__device__ __forceinline__ float bf16_f(unsigned short h) {
  return __uint_as_float(((unsigned int)h) << 16);
}

// ---------------------------------------------------------------------------
// prep: u = W_ih @ proj_W, c = W_ih @ proj_b + b_ih; qn = normalized queries;
// W_hh split into bf16 hi/lo planes (16 blocks for the split).
// ---------------------------------------------------------------------------
__global__ void prep_kernel(const float* __restrict__ Wih,
                            const float* __restrict__ projW,
                            const float* __restrict__ projb,
                            const float* __restrict__ bih,
                            const float* __restrict__ queries,
                            const float* __restrict__ Whh,
                            float* __restrict__ ws) {
  int tid = threadIdx.x;
  if (blockIdx.x == 0) {
    if (tid < 384) {
      float u = 0.f, c = 0.f;
      for (int d = 0; d < 128; ++d) {
        float w = Wih[tid * 128 + d];
        u += w * projW[d];
        c += w * projb[d];
      }
      ws[OFF_U + tid] = u;
      ws[OFF_C + tid] = c + bih[tid];
    }
  } else if (blockIdx.x == 1) {
    if (tid < 96) {
      float ss = 0.f;
      for (int d = 0; d < 128; ++d) { float q = queries[tid * 128 + d]; ss += q * q; }
      float inv = 1.f / fmaxf(sqrtf(ss), 1e-12f);
      for (int d = 0; d < 128; ++d)
        ws[OFF_QN + tid * 128 + d] = queries[tid * 128 + d] * inv;
    }
  } else {
    unsigned short* WHI = (unsigned short*)(ws + OFF_WHI);
    unsigned short* WLO = (unsigned short*)(ws + OFF_WLO);
    int base = (blockIdx.x - 2) * 3072;
    for (int i = base + tid; i < base + 3072; i += 384) {
      float w = Whh[i];
      unsigned short hi = bf16_rtn(w);
      WHI[i] = hi;
      WLO[i] = bf16_rtn(w - bf16_f(hi));
    }
  }
}

// ---------------------------------------------------------------------------
// GRU via split-bf16 MFMA, register-resident gates.
// 256 blocks x 512 threads (8 waves), 16 seqs/block, 1 block/CU.
// Wave w owns j-tiles {w, w+8, w+16} -> acc0/1/2 = gr/gz/gn for
// d = w*16 + (lane&15), s = (lane>>4)*4 + r. Gates computed in registers;
// only h (bf16 hi/lo planes, double-buffered) round-trips through LDS.
// One barrier per step.
// ---------------------------------------------------------------------------
__global__ __launch_bounds__(512, 2) void gru_kernel(const float* __restrict__ x,
                                                     const float* __restrict__ bhh,
                                                     const float* __restrict__ outW,
                                                     float* __restrict__ ws) {
  __shared__ __align__(16) unsigned short hHi[2][16 * 17 * 8];
  __shared__ __align__(16) unsigned short hLo[2][16 * 17 * 8];
  __shared__ float xsAll[16 * 65];
  __shared__ float hFin[16 * 132];

  const int tid = threadIdx.x, wave = tid >> 6, lane = tid & 63;
  const int q = lane >> 4, s15 = lane & 15;
  const int d = wave * 16 + s15;
  const unsigned short* WHI = (const unsigned short*)(ws + OFF_WHI);
  const unsigned short* WLO = (const unsigned short*)(ws + OFF_WLO);

  // persistent B fragments: tile t -> rows j = d + 128*t
  bf16x8 Bhi[3][4], Blo[3][4];
#pragma unroll
  for (int t = 0; t < 3; ++t) {
    int row = (wave + 8 * t) * 16 + s15;
#pragma unroll
    for (int c = 0; c < 4; ++c) {
      Bhi[t][c] = *(const bf16x8*)&WHI[row * 128 + c * 32 + q * 8];
      Blo[t][c] = *(const bf16x8*)&WLO[row * 128 + c * 32 + q * 8];
    }
  }
  // loop-invariant per-lane gate constants
  const float ur = ws[OFF_U + d],       uz = ws[OFF_U + 128 + d], un = ws[OFF_U + 256 + d];
  const float cr = ws[OFF_C + d] + bhh[d];
  const float cz = ws[OFF_C + 128 + d] + bhh[128 + d];
  const float cn = ws[OFF_C + 256 + d];
  const float bj2 = bhh[256 + d];

  const int seq0 = blockIdx.x * 16;
  // stage all x for this block's 16 seqs: xsAll[s*65 + t]
  for (int i = tid; i < 1024; i += 512) {
    int s = i >> 6, tt = i & 63;
    int r = (seq0 + s) * 64 + tt;
    xsAll[s * 65 + tt] = x[((r >> 15) * 512 + (r & 511)) * 64 + ((r >> 9) & 63)];
  }
  for (int i = tid; i < 2176; i += 512) { hHi[0][i] = 0; hLo[0][i] = 0; }
  __syncthreads();

  float hreg[4] = {0.f, 0.f, 0.f, 0.f};
  const int g = d >> 3, e = d & 7;

  for (int t = 0; t < 64; ++t) {
    const int rb = t & 1, wb = rb ^ 1;
    f32x4 acc0 = {0.f, 0.f, 0.f, 0.f};
    f32x4 acc1 = {0.f, 0.f, 0.f, 0.f};
    f32x4 acc2 = {0.f, 0.f, 0.f, 0.f};
#pragma unroll
    for (int c = 0; c < 4; ++c) {
      bf16x8 Ahi = *(const bf16x8*)&hHi[rb][((c * 4 + q) * 17 + s15) * 8];
      bf16x8 Alo = *(const bf16x8*)&hLo[rb][((c * 4 + q) * 17 + s15) * 8];
      acc0 = __builtin_amdgcn_mfma_f32_16x16x32_bf16(Ahi, Bhi[0][c], acc0, 0, 0, 0);
      acc1 = __builtin_amdgcn_mfma_f32_16x16x32_bf16(Ahi, Bhi[1][c], acc1, 0, 0, 0);
      acc2 = __builtin_amdgcn_mfma_f32_16x16x32_bf16(Ahi, Bhi[2][c], acc2, 0, 0, 0);
      acc0 = __builtin_amdgcn_mfma_f32_16x16x32_bf16(Alo, Bhi[0][c], acc0, 0, 0, 0);
      acc1 = __builtin_amdgcn_mfma_f32_16x16x32_bf16(Alo, Bhi[1][c], acc1, 0, 0, 0);
      acc2 = __builtin_amdgcn_mfma_f32_16x16x32_bf16(Alo, Bhi[2][c], acc2, 0, 0, 0);
      acc0 = __builtin_amdgcn_mfma_f32_16x16x32_bf16(Ahi, Blo[0][c], acc0, 0, 0, 0);
      acc1 = __builtin_amdgcn_mfma_f32_16x16x32_bf16(Ahi, Blo[1][c], acc1, 0, 0, 0);
      acc2 = __builtin_amdgcn_mfma_f32_16x16x32_bf16(Ahi, Blo[2][c], acc2, 0, 0, 0);
    }
    float xsv[4];
#pragma unroll
    for (int r = 0; r < 4; ++r) xsv[r] = xsAll[(q * 4 + r) * 65 + t];
#pragma unroll
    for (int r = 0; r < 4; ++r) {
      int s = q * 4 + r;
      float gr = fmaf(xsv[r], ur, cr + acc0[r]);
      float gz = fmaf(xsv[r], uz, cz + acc1[r]);
      float gn = fmaf(xsv[r], un, cn);
      float hn = acc2[r] + bj2;
      float rr = __builtin_amdgcn_rcpf(1.f + __expf(-gr));
      float zz = 1.f - __builtin_amdgcn_rcpf(1.f + __expf(-gz));  // zz' = 1-z
      float a = fmaf(rr, hn, gn);
      float ng = 1.f - 2.f * __builtin_amdgcn_rcpf(__expf(2.f * a) + 1.f);
      float hv = fmaf(zz, ng - hreg[r], hreg[r]);  // (1-z)*ng + z*h
      hreg[r] = hv;
      unsigned short hi = bf16_rtn(hv);
      unsigned short lo = bf16_rtn(hv - bf16_f(hi));
      int idx = (g * 17 + s) * 8 + e;
      hHi[wb][idx] = hi;
      hLo[wb][idx] = lo;
    }
    __syncthreads();
  }

  // final h -> LDS staging, then global + hv
#pragma unroll
  for (int r = 0; r < 4; ++r) hFin[(q * 4 + r) * 132 + d] = hreg[r];
  __syncthreads();
  float* h_out = ws + OFF_H;
#pragma unroll
  for (int p = 0; p < 4; ++p) {
    int item = tid + p * 512;
    int s = item >> 7, dd = item & 127;
    h_out[(seq0 + s) * 128 + dd] = hFin[s * 132 + dd];
  }
  for (int s = wave * 2; s < wave * 2 + 2; ++s) {
    float a = hFin[s * 132 + lane] * outW[lane] + hFin[s * 132 + 64 + lane] * outW[64 + lane];
    for (int off = 32; off; off >>= 1) a += __shfl_xor(a, off);
    if (lane == 0) ws[OFF_HV + seq0 + s] = a;
  }
}

// ---------------------------------------------------------------------------
// stats + router softmax: one block per b (512 threads, 4-way n split).
// Also zeroes Hmix (needed by topk's atomics).
// ---------------------------------------------------------------------------
__global__ __launch_bounds__(512) void stats_kernel(const float* __restrict__ routerW,
                                                    const float* __restrict__ routerb,
                                                    float* __restrict__ ws,
                                                    float* __restrict__ d_out) {
  int b = blockIdx.x, tid = threadIdx.x;
  float4* hm = (float4*)(ws + OFF_HMIX);
  float4 z4 = make_float4(0.f, 0.f, 0.f, 0.f);
#pragma unroll
  for (int i = 0; i < 8; ++i) hm[i * 4096 + b * 512 + tid] = z4;

  const float* h = ws + OFF_H;
  __shared__ float redS[512], redQ[512], st[256];
  __shared__ float lg[3];
  int p = tid >> 7, dd = tid & 127;
  float sum = 0.f, sq = 0.f;
  for (int i = 0; i < 128; ++i) {
    float v = h[(b * 512 + p * 128 + i) * 128 + dd];
    sum += v; sq += v * v;
  }
  redS[p * 128 + dd] = sum;
  redQ[p * 128 + dd] = sq;
  __syncthreads();
  if (tid < 128) {
    float s = redS[tid] + redS[128 + tid] + redS[256 + tid] + redS[384 + tid];
    float q2 = redQ[tid] + redQ[128 + tid] + redQ[256 + tid] + redQ[384 + tid];
    float mean = s * (1.f / 512.f);
    float var = (q2 - 512.f * mean * mean) * (1.f / 511.f);  // ddof=1
    st[tid] = mean;
    st[128 + tid] = sqrtf(fmaxf(var, 0.f));
  }
  __syncthreads();
  if (tid < 3) {
    float acc = routerb[tid];
    for (int q = 0; q < 256; ++q) acc += st[q] * routerW[tid * 256 + q];
    lg[tid] = acc;
  }
  __syncthreads();
  if (tid == 0) {
    float mx = fmaxf(lg[0], fmaxf(lg[1], lg[2]));
    float e0 = expf(lg[0] - mx), e1 = expf(lg[1] - mx), e2 = expf(lg[2] - mx);
    float inv = 1.f / (e0 + e1 + e2);
    ws[OFF_PROBS + b * 3 + 0] = e0 * inv;
    ws[OFF_PROBS + b * 3 + 1] = e1 * inv;
    ws[OFF_PROBS + b * 3 + 2] = e2 * inv;
    d_out[4096 + b * 3 + 0] = e0 * inv;
    d_out[4096 + b * 3 + 1] = e1 * inv;
    d_out[4096 + b * 3 + 2] = e2 * inv;
  }
}

// ---------------------------------------------------------------------------
// scores[b,m,e,n] = qn[m,e,:] . (space_W[m]@h[b,n] + space_b[m]) / ||hs||
// grid (b,m,nchunk) = 8*3*16; block 256 handles 2 n's at a time.
// ---------------------------------------------------------------------------
#define WP 132
__global__ __launch_bounds__(256) void scores_kernel(const float* __restrict__ spaceW,
                                                     const float* __restrict__ spaceb,
                                                     float* __restrict__ ws) {
  int bz = blockIdx.x;
  int b = bz / 48, rem = bz % 48, m = rem / 16, chunk = rem % 16;
  int n0 = chunk * 32;
  int tid = threadIdx.x;
  const float* h = ws + OFF_H;
  const float* qn = ws + OFF_QN;
  float* scores = ws + OFF_SCORES;

  __shared__ float WmL[128 * WP];
  __shared__ float hL2[2 * 128];
  __shared__ float hsL[2 * 128];
  __shared__ float spart[2 * 4 * 32];
  __shared__ float normL[2];

  for (int i = tid; i < 16384; i += 256)
    WmL[(i >> 7) * WP + (i & 127)] = spaceW[m * 16384 + i];
  __syncthreads();

  int nn = tid >> 7, k = tid & 127;
  for (int pair = 0; pair < 16; ++pair) {
    int n = n0 + pair * 2;
    hL2[tid] = h[(b * 512 + n + nn) * 128 + k];
    __syncthreads();
    float acc = spaceb[m * 128 + k];
#pragma unroll
    for (int d4 = 0; d4 < 32; ++d4) {
      float4 w4 = *(const float4*)&WmL[k * WP + d4 * 4];
      float4 h4 = *(const float4*)&hL2[nn * 128 + d4 * 4];
      acc += w4.x * h4.x + w4.y * h4.y + w4.z * h4.z + w4.w * h4.w;
    }
    hsL[nn * 128 + k] = acc;
    __syncthreads();
    if ((tid & 127) < 64) {
      int lane = tid & 63;
      float v0 = hsL[nn * 128 + lane], v1 = hsL[nn * 128 + 64 + lane];
      float ss = v0 * v0 + v1 * v1;
      for (int off = 32; off; off >>= 1) ss += __shfl_xor(ss, off);
      if (lane == 0) normL[nn] = fmaxf(sqrtf(ss), 1e-12f);
    }
    __syncthreads();
    int e = tid & 31, dq = (tid >> 5) & 3;
    float p = 0.f;
#pragma unroll 8
    for (int dd = 0; dd < 32; ++dd)
      p += qn[(m * 32 + e) * 128 + dq * 32 + dd] * hsL[nn * 128 + dq * 32 + dd];
    spart[(nn * 4 + dq) * 32 + e] = p;
    __syncthreads();
    if (tid < 64) {
      int nn2 = tid >> 5, e2 = tid & 31;
      float s = spart[(nn2 * 4 + 0) * 32 + e2] + spart[(nn2 * 4 + 1) * 32 + e2] +
                spart[(nn2 * 4 + 2) * 32 + e2] + spart[(nn2 * 4 + 3) * 32 + e2];
      scores[((b * 3 + m) * 32 + e2) * 512 + n + nn2] = s / normL[nn2];
    }
    __syncthreads();
  }
}

// ---------------------------------------------------------------------------
// top-25 per (b,m,e) row + softmax(vals/0.7) + scatter into Hmix (weighted by probs)
// ---------------------------------------------------------------------------
__global__ __launch_bounds__(256) void topk_kernel(float* __restrict__ ws) {
  int row = blockIdx.x * 4 + (threadIdx.x >> 6);  // [0,768)
  int lane = threadIdx.x & 63;
  int b = row / 96;
  int m = (row / 32) % 3;
  int e = row & 31;
  const float* sc = ws + OFF_SCORES + row * 512;
  float prob = ws[OFF_PROBS + b * 3 + m];

  float v[8];
#pragma unroll
  for (int j = 0; j < 8; ++j) v[j] = sc[j * 64 + lane];

  float selv = 0.f; int seli = 0; float maxv = 0.f;
  for (int it = 0; it < 25; ++it) {
    float bv = v[0]; int bj = 0;
#pragma unroll
    for (int j = 1; j < 8; ++j)
      if (v[j] > bv) { bv = v[j]; bj = j; }
    int bidx = bj * 64 + lane;
    for (int off = 32; off; off >>= 1) {
      float ov = __shfl_xor(bv, off);
      int oi = __shfl_xor(bidx, off);
      if (ov > bv || (ov == bv && oi < bidx)) { bv = ov; bidx = oi; }
    }
    if (lane == (bidx & 63)) v[bidx >> 6] = -INFINITY;
    if (it == 0) maxv = bv;
    if (lane == it) { selv = bv; seli = bidx; }
  }
  float ex = (lane < 25) ? __expf((selv - maxv) * (1.f / 0.7f)) : 0.f;
  float den = ex;
  for (int off = 32; off; off >>= 1) den += __shfl_xor(den, off);
  if (lane < 25)
    atomicAdd(&ws[OFF_HMIX + (b * 32 + e) * 512 + seli], prob * ex / den);
}

// ---------------------------------------------------------------------------
// ev[b,e] = sum_n Hmix[b,e,n] * hv[b,n]
// ---------------------------------------------------------------------------
__global__ void ev_kernel(float* __restrict__ ws) {
  int row = blockIdx.x * 4 + (threadIdx.x >> 6);  // [0,256)
  int lane = threadIdx.x & 63;
  int b = row >> 5;
  const float* Hm = ws + OFF_HMIX + row * 512;
  const float* hv = ws + OFF_HV + b * 512;
  float a = 0.f;
#pragma unroll
  for (int j = 0; j < 8; ++j) a += Hm[j * 64 + lane] * hv[j * 64 + lane];
  for (int off = 32; off; off >>= 1) a += __shfl_xor(a, off);
  if (lane == 0) ws[OFF_EV + row] = a;
}

// ---------------------------------------------------------------------------
// out[b,n] = alpha*(prior@hv)[b,n] + (1-alpha)*sum_e Hmix[b,e,n]*ev[b,e] + out_b
// ---------------------------------------------------------------------------
__global__ void final_kernel(const float* __restrict__ prior,
                             const float* __restrict__ outb,
                             const float* __restrict__ plog,
                             float* __restrict__ ws,
                             float* __restrict__ d_out) {
  int row = blockIdx.x * 4 + (threadIdx.x >> 6);  // [0,4096)
  int lane = threadIdx.x & 63;
  int b = row >> 9, n = row & 511;
  float alpha = 1.f / (1.f + expf(-plog[0]));
  const float* hv = ws + OFF_HV + b * 512;
  const float* pr = prior + n * 512;
  float s1 = 0.f;
#pragma unroll
  for (int j = 0; j < 8; ++j) s1 += pr[j * 64 + lane] * hv[j * 64 + lane];
  float s2 = 0.f;
  if (lane < 32) s2 = ws[OFF_HMIX + (b * 32 + lane) * 512 + n] * ws[OFF_EV + b * 32 + lane];
  float a = alpha * s1 + (1.f - alpha) * s2;
  for (int off = 32; off; off >>= 1) a += __shfl_xor(a, off);
  if (lane == 0) d_out[row] = a + outb[0];
}

// ---------------------------------------------------------------------------
extern "C" void kernel_launch(void* const* d_in, const int* in_sizes, int n_in,
                              void* d_out, int out_size, void* d_ws, size_t ws_size,
                              hipStream_t stream) {
  const float* x       = (const float*)d_in[0];
  const float* prior   = (const float*)d_in[1];
  const float* projW   = (const float*)d_in[2];
  const float* projb   = (const float*)d_in[3];
  const float* Wih     = (const float*)d_in[4];
  const float* Whh     = (const float*)d_in[5];
  const float* bih     = (const float*)d_in[6];
  const float* bhh     = (const float*)d_in[7];
  const float* spaceW  = (const float*)d_in[8];
  const float* spaceb  = (const float*)d_in[9];
  const float* routerW = (const float*)d_in[10];
  const float* routerb = (const float*)d_in[11];
  const float* outW    = (const float*)d_in[12];
  const float* outb    = (const float*)d_in[13];
  const float* plog    = (const float*)d_in[14];
  const float* queries = (const float*)d_in[15];
  float* ws  = (float*)d_ws;
  float* out = (float*)d_out;

  prep_kernel<<<18, 384, 0, stream>>>(Wih, projW, projb, bih, queries, Whh, ws);
  gru_kernel<<<256, 512, 0, stream>>>(x, bhh, outW, ws);
  stats_kernel<<<8, 512, 0, stream>>>(routerW, routerb, ws, out);
  scores_kernel<<<384, 256, 0, stream>>>(spaceW, spaceb, ws);
  topk_kernel<<<192, 256, 0, stream>>>(ws);
  ev_kernel<<<64, 256, 0, stream>>>(ws);
  final_kernel<<<1024, 256, 0, stream>>>(prior, outb, plog, ws, out);
}

// Round 5
// 219.597 us; speedup vs baseline: 3.5485x; 1.1887x over previous
//
#include <hip/hip_runtime.h>
#include <math.h>

// Problem dims
#define B_ 8
#define N_ 512
#define T_ 64
#define D_ 128
#define E_ 32
#define M_ 3
#define BN_ 4096

// ws layout (float offsets)
#define OFF_U      0          // 384
#define OFF_C      384        // 384
#define OFF_QN     768        // 3*32*128 = 12288
#define OFF_H      13056      // 4096*128 = 524288
#define OFF_PROBS  537344     // 24
#define OFF_HV     537376     // 4096
#define OFF_SCORES 541472     // 768*512 = 393216
#define OFF_HMIX   934688     // 8*32*512 = 131072
#define OFF_EV     1065760    // 256
#define OFF_WHI    1066016    // 24576 floats (49152 bf16)
#define OFF_WLO    1090592    // 24576 floats
#define OFF_SHI    1115168    // 24576 floats (spaceW hi)
#define OFF_SLO    1139744    // 24576 floats (spaceW lo)

typedef short bf16x8 __attribute__((ext_vector_type(8)));
typedef float f32x4 __attribute__((ext_vector_type(4)));

__device__ __forceinline__ unsigned short bf16_rtn(float f) {
  unsigned int u = __float_as_uint(f);
  return (unsigned short)((u + 0x7FFFu + ((u >> 16) & 1u)) >> 16);
}
__device__ __forceinline__ float bf16_f(unsigned short h) {
  return __uint_as_float(((unsigned int)h) << 16);
}

// ---------------------------------------------------------------------------
// prep: u/c; qn normalized; W_hh and space_W split into bf16 hi/lo planes.
// ---------------------------------------------------------------------------
__global__ void prep_kernel(const float* __restrict__ Wih,
                            const float* __restrict__ projW,
                            const float* __restrict__ projb,
                            const float* __restrict__ bih,
                            const float* __restrict__ queries,
                            const float* __restrict__ Whh,
                            const float* __restrict__ spaceW,
                            float* __restrict__ ws) {
  int tid = threadIdx.x;
  int bid = blockIdx.x;
  if (bid == 0) {
    if (tid < 384) {
      float u = 0.f, c = 0.f;
      for (int d = 0; d < 128; ++d) {
        float w = Wih[tid * 128 + d];
        u += w * projW[d];
        c += w * projb[d];
      }
      ws[OFF_U + tid] = u;
      ws[OFF_C + tid] = c + bih[tid];
    }
  } else if (bid == 1) {
    if (tid < 96) {
      float ss = 0.f;
      for (int d = 0; d < 128; ++d) { float q = queries[tid * 128 + d]; ss += q * q; }
      float inv = 1.f / fmaxf(sqrtf(ss), 1e-12f);
      for (int d = 0; d < 128; ++d)
        ws[OFF_QN + tid * 128 + d] = queries[tid * 128 + d] * inv;
    }
  } else if (bid < 18) {
    unsigned short* WHI = (unsigned short*)(ws + OFF_WHI);
    unsigned short* WLO = (unsigned short*)(ws + OFF_WLO);
    int base = (bid - 2) * 3072;
    for (int i = base + tid; i < base + 3072; i += 384) {
      float w = Whh[i];
      unsigned short hi = bf16_rtn(w);
      WHI[i] = hi;
      WLO[i] = bf16_rtn(w - bf16_f(hi));
    }
  } else {
    unsigned short* SHI = (unsigned short*)(ws + OFF_SHI);
    unsigned short* SLO = (unsigned short*)(ws + OFF_SLO);
    int base = (bid - 18) * 3072;
    for (int i = base + tid; i < base + 3072; i += 384) {
      float w = spaceW[i];
      unsigned short hi = bf16_rtn(w);
      SHI[i] = hi;
      SLO[i] = bf16_rtn(w - bf16_f(hi));
    }
  }
}

// ---------------------------------------------------------------------------
// GRU via split-bf16 MFMA, register-resident gates, 9 independent acc chains.
// ---------------------------------------------------------------------------
__global__ __launch_bounds__(512, 2) void gru_kernel(const float* __restrict__ x,
                                                     const float* __restrict__ bhh,
                                                     const float* __restrict__ outW,
                                                     float* __restrict__ ws) {
  __shared__ __align__(16) unsigned short hHi[2][16 * 17 * 8];
  __shared__ __align__(16) unsigned short hLo[2][16 * 17 * 8];
  __shared__ float xsAll[16 * 65];
  __shared__ float hFin[16 * 132];

  const int tid = threadIdx.x, wave = tid >> 6, lane = tid & 63;
  const int q = lane >> 4, s15 = lane & 15;
  const int d = wave * 16 + s15;
  const unsigned short* WHI = (const unsigned short*)(ws + OFF_WHI);
  const unsigned short* WLO = (const unsigned short*)(ws + OFF_WLO);

  bf16x8 Bhi[3][4], Blo[3][4];
#pragma unroll
  for (int t = 0; t < 3; ++t) {
    int row = (wave + 8 * t) * 16 + s15;
#pragma unroll
    for (int c = 0; c < 4; ++c) {
      Bhi[t][c] = *(const bf16x8*)&WHI[row * 128 + c * 32 + q * 8];
      Blo[t][c] = *(const bf16x8*)&WLO[row * 128 + c * 32 + q * 8];
    }
  }
  const float ur = ws[OFF_U + d],       uz = ws[OFF_U + 128 + d], un = ws[OFF_U + 256 + d];
  const float cr = ws[OFF_C + d] + bhh[d];
  const float cz = ws[OFF_C + 128 + d] + bhh[128 + d];
  const float cn = ws[OFF_C + 256 + d];
  const float bj2 = bhh[256 + d];

  const int seq0 = blockIdx.x * 16;
  for (int i = tid; i < 1024; i += 512) {
    int s = i >> 6, tt = i & 63;
    int r = (seq0 + s) * 64 + tt;
    xsAll[s * 65 + tt] = x[((r >> 15) * 512 + (r & 511)) * 64 + ((r >> 9) & 63)];
  }
  for (int i = tid; i < 2176; i += 512) { hHi[0][i] = 0; hLo[0][i] = 0; }
  __syncthreads();

  float hreg[4] = {0.f, 0.f, 0.f, 0.f};
  const int g = d >> 3, e = d & 7;

  for (int t = 0; t < 64; ++t) {
    const int rb = t & 1, wb = rb ^ 1;
    f32x4 a0h = {0.f,0.f,0.f,0.f}, a1h = {0.f,0.f,0.f,0.f}, a2h = {0.f,0.f,0.f,0.f};
    f32x4 a0l = {0.f,0.f,0.f,0.f}, a1l = {0.f,0.f,0.f,0.f}, a2l = {0.f,0.f,0.f,0.f};
    f32x4 a0w = {0.f,0.f,0.f,0.f}, a1w = {0.f,0.f,0.f,0.f}, a2w = {0.f,0.f,0.f,0.f};
#pragma unroll
    for (int c = 0; c < 4; ++c) {
      bf16x8 Ahi = *(const bf16x8*)&hHi[rb][((c * 4 + q) * 17 + s15) * 8];
      bf16x8 Alo = *(const bf16x8*)&hLo[rb][((c * 4 + q) * 17 + s15) * 8];
      a0h = __builtin_amdgcn_mfma_f32_16x16x32_bf16(Ahi, Bhi[0][c], a0h, 0, 0, 0);
      a1h = __builtin_amdgcn_mfma_f32_16x16x32_bf16(Ahi, Bhi[1][c], a1h, 0, 0, 0);
      a2h = __builtin_amdgcn_mfma_f32_16x16x32_bf16(Ahi, Bhi[2][c], a2h, 0, 0, 0);
      a0l = __builtin_amdgcn_mfma_f32_16x16x32_bf16(Alo, Bhi[0][c], a0l, 0, 0, 0);
      a1l = __builtin_amdgcn_mfma_f32_16x16x32_bf16(Alo, Bhi[1][c], a1l, 0, 0, 0);
      a2l = __builtin_amdgcn_mfma_f32_16x16x32_bf16(Alo, Bhi[2][c], a2l, 0, 0, 0);
      a0w = __builtin_amdgcn_mfma_f32_16x16x32_bf16(Ahi, Blo[0][c], a0w, 0, 0, 0);
      a1w = __builtin_amdgcn_mfma_f32_16x16x32_bf16(Ahi, Blo[1][c], a1w, 0, 0, 0);
      a2w = __builtin_amdgcn_mfma_f32_16x16x32_bf16(Ahi, Blo[2][c], a2w, 0, 0, 0);
    }
    float xsv[4];
#pragma unroll
    for (int r = 0; r < 4; ++r) xsv[r] = xsAll[(q * 4 + r) * 65 + t];
#pragma unroll
    for (int r = 0; r < 4; ++r) {
      int s = q * 4 + r;
      float acc0 = a0h[r] + a0l[r] + a0w[r];
      float acc1 = a1h[r] + a1l[r] + a1w[r];
      float acc2 = a2h[r] + a2l[r] + a2w[r];
      float gr = fmaf(xsv[r], ur, cr + acc0);
      float gz = fmaf(xsv[r], uz, cz + acc1);
      float gn = fmaf(xsv[r], un, cn);
      float hn = acc2 + bj2;
      float rr = __builtin_amdgcn_rcpf(1.f + __expf(-gr));
      float zz = 1.f - __builtin_amdgcn_rcpf(1.f + __expf(-gz));  // 1-z
      float a = fmaf(rr, hn, gn);
      float ng = 1.f - 2.f * __builtin_amdgcn_rcpf(__expf(2.f * a) + 1.f);
      float hv = fmaf(zz, ng - hreg[r], hreg[r]);
      hreg[r] = hv;
      unsigned short hi = bf16_rtn(hv);
      unsigned short lo = bf16_rtn(hv - bf16_f(hi));
      int idx = (g * 17 + s) * 8 + e;
      hHi[wb][idx] = hi;
      hLo[wb][idx] = lo;
    }
    __syncthreads();
  }

#pragma unroll
  for (int r = 0; r < 4; ++r) hFin[(q * 4 + r) * 132 + d] = hreg[r];
  __syncthreads();
  float* h_out = ws + OFF_H;
#pragma unroll
  for (int p = 0; p < 4; ++p) {
    int item = tid + p * 512;
    int s = item >> 7, dd = item & 127;
    h_out[(seq0 + s) * 128 + dd] = hFin[s * 132 + dd];
  }
  for (int s = wave * 2; s < wave * 2 + 2; ++s) {
    float a = hFin[s * 132 + lane] * outW[lane] + hFin[s * 132 + 64 + lane] * outW[64 + lane];
    for (int off = 32; off; off >>= 1) a += __shfl_xor(a, off);
    if (lane == 0) ws[OFF_HV + seq0 + s] = a;
  }
}

// ---------------------------------------------------------------------------
// stats + router softmax: one block per b, 1024 threads (8-way n split).
// Also zeroes Hmix slice for topk's atomics.
// ---------------------------------------------------------------------------
__global__ __launch_bounds__(1024) void stats_kernel(const float* __restrict__ routerW,
                                                     const float* __restrict__ routerb,
                                                     float* __restrict__ ws,
                                                     float* __restrict__ d_out) {
  int b = blockIdx.x, tid = threadIdx.x;
  float4* hm4 = (float4*)(ws + OFF_HMIX);
  float4 z4 = make_float4(0.f, 0.f, 0.f, 0.f);
  for (int i = tid; i < 4096; i += 1024) hm4[b * 4096 + i] = z4;

  const float* h = ws + OFF_H;
  __shared__ float redS[1024], redQ[1024], st[256];
  __shared__ float lg[3];
  int p = tid >> 7, dd = tid & 127;
  float sum = 0.f, sq = 0.f;
  for (int i = 0; i < 64; ++i) {
    float v = h[(b * 512 + p * 64 + i) * 128 + dd];
    sum += v; sq += v * v;
  }
  redS[p * 128 + dd] = sum;
  redQ[p * 128 + dd] = sq;
  __syncthreads();
  if (tid < 128) {
    float s = 0.f, q2 = 0.f;
#pragma unroll
    for (int j = 0; j < 8; ++j) { s += redS[j * 128 + tid]; q2 += redQ[j * 128 + tid]; }
    float mean = s * (1.f / 512.f);
    float var = (q2 - 512.f * mean * mean) * (1.f / 511.f);  // ddof=1
    st[tid] = mean;
    st[128 + tid] = sqrtf(fmaxf(var, 0.f));
  }
  __syncthreads();
  if (tid < 3) {
    float acc = routerb[tid];
    for (int q = 0; q < 256; ++q) acc += st[q] * routerW[tid * 256 + q];
    lg[tid] = acc;
  }
  __syncthreads();
  if (tid == 0) {
    float mx = fmaxf(lg[0], fmaxf(lg[1], lg[2]));
    float e0 = expf(lg[0] - mx), e1 = expf(lg[1] - mx), e2 = expf(lg[2] - mx);
    float inv = 1.f / (e0 + e1 + e2);
    ws[OFF_PROBS + b * 3 + 0] = e0 * inv;
    ws[OFF_PROBS + b * 3 + 1] = e1 * inv;
    ws[OFF_PROBS + b * 3 + 2] = e2 * inv;
    d_out[4096 + b * 3 + 0] = e0 * inv;
    d_out[4096 + b * 3 + 1] = e1 * inv;
    d_out[4096 + b * 3 + 2] = e2 * inv;
  }
}

// ---------------------------------------------------------------------------
// scores via split-bf16 MFMA. Grid 384 = (b,m,chunk of 32 n). Block 256.
// hs[n][dout] = sum_d h[n,d] W[m,dout,d] + b[m,dout]  (C: row=n, col=dout)
// then norm over dout, then scores[e][n] = qn[e,:]·hs[n,:] / norm[n].
// ---------------------------------------------------------------------------
__global__ __launch_bounds__(256) void scores_kernel(const float* __restrict__ spaceb,
                                                     float* __restrict__ ws) {
  const int bid = blockIdx.x;
  const int chunk = bid & 15, m = (bid >> 4) % 3, b = bid / 48;
  const int n0 = chunk * 32;
  const int tid = threadIdx.x, wave = tid >> 6, lane = tid & 63;
  const int q = lane >> 4, s15 = lane & 15;

  __shared__ __align__(16) unsigned short sHi[16 * 33 * 8];
  __shared__ __align__(16) unsigned short sLo[16 * 33 * 8];
  __shared__ float hsL[32 * 132];
  __shared__ float biasL[128];
  __shared__ float invnL[32];

  const float* hG = ws + OFF_H;
  const unsigned short* SHI = (const unsigned short*)(ws + OFF_SHI);
  const unsigned short* SLO = (const unsigned short*)(ws + OFF_SLO);

  if (tid < 128) biasL[tid] = spaceb[m * 128 + tid];
  // stage h[b, n0..n0+31, :] as bf16 hi/lo in A-frag cells (g=k>>3, n), pitch 33
  {
    int nn = tid >> 3, kc = tid & 7;
    const float* row = &hG[(b * 512 + n0 + nn) * 128 + kc * 16];
    union { unsigned short s[8]; uint4 v; } ph0, pl0, ph1, pl1;
#pragma unroll
    for (int j = 0; j < 8; ++j) {
      float v = row[j];
      unsigned short hi = bf16_rtn(v);
      ph0.s[j] = hi; pl0.s[j] = bf16_rtn(v - bf16_f(hi));
    }
#pragma unroll
    for (int j = 0; j < 8; ++j) {
      float v = row[8 + j];
      unsigned short hi = bf16_rtn(v);
      ph1.s[j] = hi; pl1.s[j] = bf16_rtn(v - bf16_f(hi));
    }
    int g0 = kc * 2;
    *(uint4*)&sHi[(g0 * 33 + nn) * 8] = ph0.v;
    *(uint4*)&sLo[(g0 * 33 + nn) * 8] = pl0.v;
    *(uint4*)&sHi[((g0 + 1) * 33 + nn) * 8] = ph1.v;
    *(uint4*)&sLo[((g0 + 1) * 33 + nn) * 8] = pl1.v;
  }
  __syncthreads();

  // wave -> n-tile nt = wave>>1 (16 n), d-tiles dt = (wave&1)*4 + 0..3
  const int nt = wave >> 1;
  const int dt0 = (wave & 1) * 4;
  f32x4 acc[4] = {{0.f,0.f,0.f,0.f},{0.f,0.f,0.f,0.f},{0.f,0.f,0.f,0.f},{0.f,0.f,0.f,0.f}};
#pragma unroll
  for (int c = 0; c < 4; ++c) {
    bf16x8 Ahi = *(const bf16x8*)&sHi[((c * 4 + q) * 33 + nt * 16 + s15) * 8];
    bf16x8 Alo = *(const bf16x8*)&sLo[((c * 4 + q) * 33 + nt * 16 + s15) * 8];
#pragma unroll
    for (int i = 0; i < 4; ++i) {
      int row = m * 16384 + ((dt0 + i) * 16 + s15) * 128 + c * 32 + q * 8;
      bf16x8 Bhi = *(const bf16x8*)&SHI[row];
      bf16x8 Blo = *(const bf16x8*)&SLO[row];
      acc[i] = __builtin_amdgcn_mfma_f32_16x16x32_bf16(Ahi, Bhi, acc[i], 0, 0, 0);
      acc[i] = __builtin_amdgcn_mfma_f32_16x16x32_bf16(Alo, Bhi, acc[i], 0, 0, 0);
      acc[i] = __builtin_amdgcn_mfma_f32_16x16x32_bf16(Ahi, Blo, acc[i], 0, 0, 0);
    }
  }
  // store hs tiles: n = nt*16 + q*4 + r, dout = (dt0+i)*16 + s15
#pragma unroll
  for (int i = 0; i < 4; ++i) {
    int dcol = (dt0 + i) * 16 + s15;
    float bb = biasL[dcol];
#pragma unroll
    for (int r = 0; r < 4; ++r)
      hsL[(nt * 16 + q * 4 + r) * 132 + dcol] = acc[i][r] + bb;
  }
  __syncthreads();

  // norms: thread (n = tid>>3, kc = tid&7) sums 16 douts; reduce over 8 lanes
  {
    int n = tid >> 3, kc = tid & 7;
    float ss = 0.f;
#pragma unroll
    for (int d4 = 0; d4 < 4; ++d4) {
      float4 v = *(const float4*)&hsL[n * 132 + kc * 16 + d4 * 4];
      ss += v.x * v.x + v.y * v.y + v.z * v.z + v.w * v.w;
    }
    ss += __shfl_xor(ss, 1); ss += __shfl_xor(ss, 2); ss += __shfl_xor(ss, 4);
    if (kc == 0) invnL[n] = 1.f / fmaxf(sqrtf(ss), 1e-12f);
  }
  __syncthreads();

  // scores: thread (n = tid&31, eg = tid>>5): e = eg*4 + i
  {
    int n = tid & 31, eg = tid >> 5;
    const float* qn = ws + OFF_QN + (m * 32 + eg * 4) * 128;
    float a0 = 0.f, a1 = 0.f, a2 = 0.f, a3 = 0.f;
#pragma unroll
    for (int d4 = 0; d4 < 32; ++d4) {
      float4 hv = *(const float4*)&hsL[n * 132 + d4 * 4];
      float4 q0 = *(const float4*)&qn[d4 * 4];
      float4 q1 = *(const float4*)&qn[128 + d4 * 4];
      float4 q2 = *(const float4*)&qn[256 + d4 * 4];
      float4 q3 = *(const float4*)&qn[384 + d4 * 4];
      a0 += hv.x * q0.x + hv.y * q0.y + hv.z * q0.z + hv.w * q0.w;
      a1 += hv.x * q1.x + hv.y * q1.y + hv.z * q1.z + hv.w * q1.w;
      a2 += hv.x * q2.x + hv.y * q2.y + hv.z * q2.z + hv.w * q2.w;
      a3 += hv.x * q3.x + hv.y * q3.y + hv.z * q3.z + hv.w * q3.w;
    }
    float inv = invnL[n];
    float* sc = ws + OFF_SCORES + ((b * 3 + m) * 32 + eg * 4) * 512 + n0 + n;
    sc[0]    = a0 * inv;
    sc[512]  = a1 * inv;
    sc[1024] = a2 * inv;
    sc[1536] = a3 * inv;
  }
}

// ---------------------------------------------------------------------------
// top-25 per (b,m,e) row + softmax(vals/0.7) + scatter into Hmix (× probs)
// ---------------------------------------------------------------------------
__global__ __launch_bounds__(256) void topk_kernel(float* __restrict__ ws) {
  int row = blockIdx.x * 4 + (threadIdx.x >> 6);  // [0,768)
  int lane = threadIdx.x & 63;
  int b = row / 96;
  int m = (row / 32) % 3;
  int e = row & 31;
  const float* sc = ws + OFF_SCORES + row * 512;
  float prob = ws[OFF_PROBS + b * 3 + m];

  float v[8];
#pragma unroll
  for (int j = 0; j < 8; ++j) v[j] = sc[j * 64 + lane];

  float selv = 0.f; int seli = 0; float maxv = 0.f;
  for (int it = 0; it < 25; ++it) {
    float bv = v[0]; int bj = 0;
#pragma unroll
    for (int j = 1; j < 8; ++j)
      if (v[j] > bv) { bv = v[j]; bj = j; }
    int bidx = bj * 64 + lane;
    for (int off = 32; off; off >>= 1) {
      float ov = __shfl_xor(bv, off);
      int oi = __shfl_xor(bidx, off);
      if (ov > bv || (ov == bv && oi < bidx)) { bv = ov; bidx = oi; }
    }
    if (lane == (bidx & 63)) v[bidx >> 6] = -INFINITY;
    if (it == 0) maxv = bv;
    if (lane == it) { selv = bv; seli = bidx; }
  }
  float ex = (lane < 25) ? __expf((selv - maxv) * (1.f / 0.7f)) : 0.f;
  float den = ex;
  for (int off = 32; off; off >>= 1) den += __shfl_xor(den, off);
  if (lane < 25)
    atomicAdd(&ws[OFF_HMIX + (b * 32 + e) * 512 + seli], prob * ex / den);
}

// ---------------------------------------------------------------------------
// ev[b,e] = sum_n Hmix[b,e,n] * hv[b,n]
// ---------------------------------------------------------------------------
__global__ void ev_kernel(float* __restrict__ ws) {
  int row = blockIdx.x * 4 + (threadIdx.x >> 6);  // [0,256)
  int lane = threadIdx.x & 63;
  int b = row >> 5;
  const float* Hm = ws + OFF_HMIX + row * 512;
  const float* hv = ws + OFF_HV + b * 512;
  float a = 0.f;
#pragma unroll
  for (int j = 0; j < 8; ++j) a += Hm[j * 64 + lane] * hv[j * 64 + lane];
  for (int off = 32; off; off >>= 1) a += __shfl_xor(a, off);
  if (lane == 0) ws[OFF_EV + row] = a;
}

// ---------------------------------------------------------------------------
// out[b,n] = alpha*(prior@hv)[b,n] + (1-alpha)*sum_e Hmix[b,e,n]*ev[b,e] + out_b
// ---------------------------------------------------------------------------
__global__ void final_kernel(const float* __restrict__ prior,
                             const float* __restrict__ outb,
                             const float* __restrict__ plog,
                             float* __restrict__ ws,
                             float* __restrict__ d_out) {
  int row = blockIdx.x * 4 + (threadIdx.x >> 6);  // [0,4096)
  int lane = threadIdx.x & 63;
  int b = row >> 9, n = row & 511;
  float alpha = 1.f / (1.f + expf(-plog[0]));
  const float* hv = ws + OFF_HV + b * 512;
  const float* pr = prior + n * 512;
  float s1 = 0.f;
#pragma unroll
  for (int j = 0; j < 8; ++j) s1 += pr[j * 64 + lane] * hv[j * 64 + lane];
  float s2 = 0.f;
  if (lane < 32) s2 = ws[OFF_HMIX + (b * 32 + lane) * 512 + n] * ws[OFF_EV + b * 32 + lane];
  float a = alpha * s1 + (1.f - alpha) * s2;
  for (int off = 32; off; off >>= 1) a += __shfl_xor(a, off);
  if (lane == 0) d_out[row] = a + outb[0];
}

// ---------------------------------------------------------------------------
extern "C" void kernel_launch(void* const* d_in, const int* in_sizes, int n_in,
                              void* d_out, int out_size, void* d_ws, size_t ws_size,
                              hipStream_t stream) {
  const float* x       = (const float*)d_in[0];
  const float* prior   = (const float*)d_in[1];
  const float* projW   = (const float*)d_in[2];
  const float* projb   = (const float*)d_in[3];
  const float* Wih     = (const float*)d_in[4];
  const float* Whh     = (const float*)d_in[5];
  const float* bih     = (const float*)d_in[6];
  const float* bhh     = (const float*)d_in[7];
  const float* spaceW  = (const float*)d_in[8];
  const float* spaceb  = (const float*)d_in[9];
  const float* routerW = (const float*)d_in[10];
  const float* routerb = (const float*)d_in[11];
  const float* outW    = (const float*)d_in[12];
  const float* outb    = (const float*)d_in[13];
  const float* plog    = (const float*)d_in[14];
  const float* queries = (const float*)d_in[15];
  float* ws  = (float*)d_ws;
  float* out = (float*)d_out;

  prep_kernel<<<34, 384, 0, stream>>>(Wih, projW, projb, bih, queries, Whh, spaceW, ws);
  gru_kernel<<<256, 512, 0, stream>>>(x, bhh, outW, ws);
  stats_kernel<<<8, 1024, 0, stream>>>(routerW, routerb, ws, out);
  scores_kernel<<<384, 256, 0, stream>>>(spaceb, ws);
  topk_kernel<<<192, 256, 0, stream>>>(ws);
  ev_kernel<<<64, 256, 0, stream>>>(ws);
  final_kernel<<<1024, 256, 0, stream>>>(prior, outb, plog, ws, out);
}